// Round 11
// baseline (2472.106 us; speedup 1.0000x reference)
//
#include <hip/hip_runtime.h>
#include <hip/hip_bf16.h>

// RNN: B=4096, T=1024, H=40, K=41. fp32 compute & state (dtype autodetected).
// Round-11 = round-10 (proven: 878us) + forced weight residency.
//   1024 blocks x 128 thr (2 waves), 4 els/block -> 4 blocks/CU (8 waves/CU).
//   amdgpu_waves_per_eu(2,2): allocator may use up to 256 VGPR so the 4
//   weight rows (~220 live floats) stay in VGPRs (round-10: capped at 128 ->
//   per-step AGPR/L1 reload traffic ~700 cyc/SIMD of the 2133-cyc step).
//   el = lane&3, worker w = wv*16 + (lane>>2)  (0..31).
//   Wave 0: A rows {3w..3w+2}; B: w<8 -> row 32+w, w==8 -> row 40=OUT (o-acts).
//   Wave 1: A rows {48+2(w-16),+1}; B rows {2(w-16),+1}.
//   Even/odd dual accumulators per row (shorter chains; pk_fma-friendly).
//   LDS = state only; 2 barriers/step. Dual-template dtype safety.

#define B_SZ 4096
#define T_SZ 1024
#define HID  40

typedef unsigned short u16;
typedef unsigned int   u32;

__device__ __forceinline__ float bf2f(u16 v) {
  union { u32 u; float f; } c; c.u = ((u32)v) << 16; return c.f;
}

template <bool BF>
__device__ __forceinline__ float ldg(const void* p, long i) {
  if (BF) return bf2f(((const u16*)p)[i]);
  return ((const float*)p)[i];
}

// Proven rounds 3-10: true-bf16 weights all have |w| <= 1/sqrt(41) ~ 0.156;
// fp32 data read as bf16 halfwords exceeds 0.2 with P ~ 1-1e-10.
__device__ __forceinline__ bool detect_bf16(const void* w) {
  const u16* p = (const u16*)w;
  bool bf = true;
  for (int i = 0; i < 64; ++i) {
    float f = bf2f(p[i]);
    if (!(fabsf(f) <= 0.2f)) bf = false;
  }
  return bf;
}

template <bool BF>
__global__ __launch_bounds__(128)
__attribute__((amdgpu_waves_per_eu(2, 2)))
void rnn_kernel(const void* __restrict__ inp,
                const void* __restrict__ h2h_w1, const void* __restrict__ h2h_b1,
                const void* __restrict__ h2h_w2, const void* __restrict__ h2h_b2,
                const void* __restrict__ h2o_w1, const void* __restrict__ h2o_b1,
                const void* __restrict__ h2o_w2, const void* __restrict__ h2o_b2,
                void* __restrict__ out) {
  __shared__ __align__(16) float sH[4][44];  // [el][k]  (bank-disjoint per el)
  __shared__ __align__(16) float sA[4][84];  // [el][j]  (bank-disjoint per el)

  if (detect_bf16(h2h_w1) != BF) return;  // wrong-dtype instantiation exits

  const int tid  = threadIdx.x;
  const int lane = tid & 63;
  const int wv   = tid >> 6;                // 0..1 (wave-uniform)
  const int el   = lane & 3;
  const int w    = wv * 16 + (lane >> 2);   // 0..31

  // Row maps (round-10-proven coverage: A 0..79 once; B 0..40 once)
  const int a0 = (wv == 0) ? 3 * w : 48 + 2 * (w - 16);
  const int nA = (wv == 0) ? 3 : 2;
  const int rB = (wv == 0) ? ((w < 8) ? 32 + w : ((w == 8) ? 40 : -1)) : 2 * (w - 16);

  // ---- Load exactly 4 weight rows per thread (uniform liveness) ----
  float4 w4[4][10];
  float  wu[3], ba[3], bb[2];
  {
    const int a2 = (nA == 3) ? a0 + 2 : a0;  // dummy repeat for wave-1 3rd slot
    const int ja[3] = {a0, a0 + 1, a2};
#pragma unroll
    for (int q = 0; q < 3; ++q) {
      const int  j  = ja[q];
      const bool hh = (j < HID);
      const void* wb1 = hh ? h2h_w1 : h2o_w1;
      const long  jr  = hh ? j : (j - HID);
      wu[q] = ldg<BF>(wb1, jr * 41);
      ba[q] = ldg<BF>(hh ? h2h_b1 : h2o_b1, jr);
#pragma unroll
      for (int i = 0; i < 10; ++i) {
        w4[q][i].x = ldg<BF>(wb1, jr * 41 + 1 + 4 * i);
        w4[q][i].y = ldg<BF>(wb1, jr * 41 + 2 + 4 * i);
        w4[q][i].z = ldg<BF>(wb1, jr * 41 + 3 + 4 * i);
        w4[q][i].w = ldg<BF>(wb1, jr * 41 + 4 + 4 * i);
      }
    }
  }
  if (wv == 0) {
    const int  rE    = (rB < 0) ? 32 : rB;   // dummy row for idle workers
    const bool isout = (rE == 40);
    const void* wb2  = isout ? h2o_w2 : h2h_w2;
    const long  rr   = isout ? 0 : rE;
    bb[0] = isout ? ldg<BF>(h2o_b2, 0) : ldg<BF>(h2h_b2, rE);
    bb[1] = 0.f;
#pragma unroll
    for (int i = 0; i < 10; ++i) {
      w4[3][i].x = ldg<BF>(wb2, rr * 40 + 4 * i);
      w4[3][i].y = ldg<BF>(wb2, rr * 40 + 4 * i + 1);
      w4[3][i].z = ldg<BF>(wb2, rr * 40 + 4 * i + 2);
      w4[3][i].w = ldg<BF>(wb2, rr * 40 + 4 * i + 3);
    }
  } else {
#pragma unroll
    for (int q = 0; q < 2; ++q) {
      const long r = rB + q;
      bb[q] = ldg<BF>(h2h_b2, r);
#pragma unroll
      for (int i = 0; i < 10; ++i) {
        w4[2 + q][i].x = ldg<BF>(h2h_w2, r * 40 + 4 * i);
        w4[2 + q][i].y = ldg<BF>(h2h_w2, r * 40 + 4 * i + 1);
        w4[2 + q][i].z = ldg<BF>(h2h_w2, r * 40 + 4 * i + 2);
        w4[2 + q][i].w = ldg<BF>(h2h_w2, r * 40 + 4 * i + 3);
      }
    }
  }

  for (int i = tid; i < 4 * 44; i += 128) ((float*)sH)[i] = 0.f;
  __syncthreads();

  const int  b    = blockIdx.x * 4 + el;
  const long base = (long)b * T_SZ;
  float u_cur = ldg<BF>(inp, base);

  for (int t = 0; t < T_SZ; ++t) {
    const float u_nxt = (t + 1 < T_SZ) ? ldg<BF>(inp, base + t + 1) : 0.f;

    // ---------- Phase A: layer 1 (80 neurons) ----------
    float4 hv[10];
    {
      const float4* hp = (const float4*)sH[el];
#pragma unroll
      for (int i = 0; i < 10; ++i) hv[i] = hp[i];
    }
#pragma unroll
    for (int q = 0; q < 3; ++q) {
      if (q < nA) {   // wave-uniform
        float e = fmaf(u_cur, wu[q], ba[q]);   // even chain
        float o = 0.f;                          // odd chain
#pragma unroll
        for (int i = 0; i < 10; ++i) {
          e = fmaf(hv[i].x, w4[q][i].x, e);
          o = fmaf(hv[i].y, w4[q][i].y, o);
          e = fmaf(hv[i].z, w4[q][i].z, e);
          o = fmaf(hv[i].w, w4[q][i].w, o);
        }
        const float a = e + o;
        sA[el][a0 + q] = fmaxf(a, 0.01f * a);   // LeakyReLU(0.01)
      }
    }
    __syncthreads();   // sA visible; all sH reads done

    // ---------- Phase B: layer 2 (rows 0..39 = hidden, 40 = output) ----------
    if (wv == 1) {     // uniform: 2 rows, a-acts
      float4 av[10];
      {
        const float4* ap = (const float4*)sA[el];
#pragma unroll
        for (int i = 0; i < 10; ++i) av[i] = ap[i];
      }
#pragma unroll
      for (int q = 0; q < 2; ++q) {
        float e = bb[q], o = 0.f;
#pragma unroll
        for (int i = 0; i < 10; ++i) {
          e = fmaf(av[i].x, w4[2 + q][i].x, e);
          o = fmaf(av[i].y, w4[2 + q][i].y, o);
          e = fmaf(av[i].z, w4[2 + q][i].z, e);
          o = fmaf(av[i].w, w4[2 + q][i].w, o);
        }
        sH[el][rB + q] = e + o;
      }
    } else if (rB >= 0) {   // wave 0: one row (32..39) or output row 40
      const float4* ap = (const float4*)(&sA[el][(rB == 40) ? 40 : 0]);
      float e = bb[0], o = 0.f;
#pragma unroll
      for (int i = 0; i < 10; ++i) {
        const float4 a4 = ap[i];
        e = fmaf(a4.x, w4[3][i].x, e);
        o = fmaf(a4.y, w4[3][i].y, o);
        e = fmaf(a4.z, w4[3][i].z, e);
        o = fmaf(a4.w, w4[3][i].w, o);
      }
      const float a2 = e + o;
      if (rB < HID) {
        sH[el][rB] = a2;
      } else {
        if (BF) ((__hip_bfloat16*)out)[base + t] = __float2bfloat16(a2);
        else    ((float*)out)[base + t] = a2;
      }
    }
    __syncthreads();   // sH update + sA reads done before next step

    u_cur = u_nxt;
  }
}

extern "C" void kernel_launch(void* const* d_in, const int* in_sizes, int n_in,
                              void* d_out, int out_size, void* d_ws, size_t ws_size,
                              hipStream_t stream) {
  (void)in_sizes; (void)n_in; (void)out_size; (void)d_ws; (void)ws_size;
  rnn_kernel<false><<<dim3(B_SZ / 4), dim3(128), 0, stream>>>(
      d_in[0], d_in[1], d_in[2], d_in[3], d_in[4],
      d_in[5], d_in[6], d_in[7], d_in[8], d_out);
  rnn_kernel<true><<<dim3(B_SZ / 4), dim3(128), 0, stream>>>(
      d_in[0], d_in[1], d_in[2], d_in[3], d_in[4],
      d_in[5], d_in[6], d_in[7], d_in[8], d_out);
}